// Round 8
// baseline (3600.209 us; speedup 1.0000x reference)
//
#include <hip/hip_runtime.h>

// MyLSTM_GCN: B=4096, T=128, H=156, L=2, O=12
// R10: minimal-delta = R5's verified sync/staging skeleton + frag-major LDS.
//  R9 lesson: lgkm-only barriers broke inter-WG L2 temporal coalescing of the
//  weight stream (FETCH 4.9e5 -> 4.5e6 KB, time 2.43 -> 3.53 ms). R5's full
//  __syncthreads() drains throttle WGs into lockstep -> 96% L2 hit. Keep that.
//  Kept from R8/R9 (verified good): frag-major state/x LDS (bank conflicts
//  1.66e8 -> 5.0e7), A-frag register reuse, GCN'd c in registers, merged-free
//  per-S GCN with single tmp buffer.
//  Ledger (R5-proven, uniform all t): mats 0,1 staged in phase A (drained at
//  B1); in-loop stage m+2 for m<6; i0..i6 vmcnt(5), i7 vmcnt(0).

#define HH 156
#define HP 160
#define TT 128
#define OO 12
#define BB 32             // batches per WG
#define MATSZ 25600       // 160x160 f16 per gate/adj matrix, frag-major
#define FMAT  5120        // 32x160 f16 per frag-major state matrix

typedef _Float16 f16x8 __attribute__((ext_vector_type(8)));
typedef _Float16 f16x4 __attribute__((ext_vector_type(4)));
typedef float    f32x4 __attribute__((ext_vector_type(4)));

__device__ __forceinline__ float sigm(float v) { return 1.0f / (1.0f + __expf(-v)); }
__device__ __forceinline__ float tanh_(float v) { return 2.0f / (1.0f + __expf(-2.0f * v)) - 1.0f; }

// ---------------------------------------------------------------------------
// Phase 0 (unchanged, verified): 17 matrices frag-major f16 + combined biases.
// mat id: 0 = adj; 1 + j*8 + (g*2+s), g: i,f,o,c; s=0:Wx,1:Wh.
// ---------------------------------------------------------------------------
__global__ __launch_bounds__(256) void prep_kernel(
    const float* __restrict__ adj,
    const float* __restrict__ Wix, const float* __restrict__ Wih,
    const float* __restrict__ Wfx, const float* __restrict__ Wfh,
    const float* __restrict__ Wcx, const float* __restrict__ Wch,
    const float* __restrict__ Wox, const float* __restrict__ Woh,
    const float* __restrict__ bix, const float* __restrict__ bih,
    const float* __restrict__ bfx, const float* __restrict__ bfh,
    const float* __restrict__ bcx, const float* __restrict__ bch,
    const float* __restrict__ box_, const float* __restrict__ boh,
    _Float16* __restrict__ wmats, float* __restrict__ bias_comb)
{
    int idx = blockIdx.x * 256 + threadIdx.x;
    if (idx < 17 * MATSZ) {
        int mat = idx / MATSZ;
        int r   = idx % MATSZ;
        int e    = r & 7;
        int lane = (r >> 3) & 63;
        int c    = r >> 9;            // 0..49
        int lcol = lane & 15, quad = lane >> 4;
        int kk = c % 5, w = c / 5;
        int nrow = w * 16 + lcol;
        int k    = kk * 32 + quad * 8 + e;
        float v = 0.f;
        if (nrow < HH && k < HH) {
            if (mat == 0) {
                v = adj[nrow * HH + k];
            } else {
                int m2 = mat - 1;
                int s  = m2 & 1;
                int jg = m2 >> 1;
                int j  = jg >> 2;
                int g  = jg & 3;
                const float* W;
                if (s == 0) W = (g == 0) ? Wix : (g == 1) ? Wfx : (g == 2) ? Wox : Wcx;
                else        W = (g == 0) ? Wih : (g == 1) ? Wfh : (g == 2) ? Woh : Wch;
                v = W[j * (HH * HH) + nrow * HH + k];
            }
        }
        wmats[idx] = (_Float16)v;
    } else if (idx < 17 * MATSZ + 2 * 4 * HP) {
        int r = idx - 17 * MATSZ;
        int j = r / (4 * HP);
        int g = (r % (4 * HP)) / HP;
        int nn = r % HP;
        float v = 0.f;
        if (nn < HH) {
            const float* Bx = (g == 0) ? bix : (g == 1) ? bfx : (g == 2) ? box_ : bcx;
            const float* Bh = (g == 0) ? bih : (g == 1) ? bfh : (g == 2) ? boh : bch;
            v = Bx[j * HH + nn] + Bh[j * HH + nn];
        }
        bias_comb[r] = v;
    }
}

// async 16B/lane DMA: lane L reads g+L*16B, writes wave-uniform ldsbase + L*16B
__device__ __forceinline__ void dma16(const _Float16* g, _Float16* l) {
    __builtin_amdgcn_global_load_lds(
        (const __attribute__((address_space(1))) void*)(g),
        (__attribute__((address_space(3))) void*)(l), 16, 0, 0);
}

// stage one frag-major matrix: wave w copies its own chunks w*5..w*5+4 (1KB each)
__device__ __forceinline__ void stage_mat(_Float16* buf, const _Float16* gmat,
                                          int wave, int lane) {
    #pragma unroll
    for (int i = 0; i < 5; ++i) {
        const int c = wave * 5 + i;
        dma16(gmat + (size_t)c * 512 + lane * 8, buf + (size_t)c * 512);
    }
}

// f16 index of element (row m, col k) in a 32x160 frag-major matrix
__device__ __forceinline__ int fidx(int m, int k) {
    return (((m >> 4) * 5 + (k >> 5)) * 64 + ((k >> 3) & 3) * 16 + (m & 15)) * 8 + (k & 7);
}

// ---------------------------------------------------------------------------
// Main recurrent kernel: 256 WGs x 640 threads (10 waves, 1 WG/CU).
// bid&1 = layer, bid>>1 = batch group (M=32). Wave w owns cols n = w*16+lcol.
// ---------------------------------------------------------------------------
__global__ __launch_bounds__(640, 3) void lstm_main(
    const float* __restrict__ x,
    const _Float16* __restrict__ wmats,
    const float* __restrict__ bias_comb,
    const float* __restrict__ w_out,
    const float* __restrict__ b_out,
    const float* __restrict__ gcn_w1,
    const float* __restrict__ gcn_w2,
    float* __restrict__ out)
{
    __shared__ __align__(16) _Float16 st_c[FMAT];       // frag-major 32x160
    __shared__ __align__(16) _Float16 st_h[FMAT];
    __shared__ __align__(16) _Float16 tmp[FMAT];        // GCN mid, per-S
    __shared__ __align__(16) _Float16 xbf[FMAT];
    __shared__ __align__(16) _Float16 wout_s[OO][TT + 8];
    extern __shared__ __align__(16) _Float16 wbuf[];    // 2 x 25600 f16 (100 KB)

    const int tid   = threadIdx.x;
    const int wave  = tid >> 6;
    const int lane  = tid & 63;
    const int lcol  = lane & 15;
    const int quad  = lane >> 4;
    const int qoff  = quad << 3;
    const int layer = blockIdx.x & 1;
    const int b0    = (blockIdx.x >> 1) << 5;
    const int n     = (wave << 4) + lcol;
    // frag col-base for scalar writes at col n: fidx(m,n) = (m>>4)*2560 + colb + (m&15)*8
    const int colb  = ((n >> 5) * 64 + ((n >> 3) & 3) * 16) * 8 + (n & 7);

    for (int e = tid; e < FMAT; e += 640) {
        st_c[e] = (_Float16)0.f;
        st_h[e] = (_Float16)0.f;
    }
    for (int e = tid; e < OO * TT; e += 640) wout_s[e / TT][e % TT] = (_Float16)w_out[e];

    float bias_r[4];
    #pragma unroll
    for (int g = 0; g < 4; ++g)
        bias_r[g] = bias_comb[(layer * 4 + g) * HP + n];
    const float gw1 = gcn_w1[layer];
    const float gw2 = gcn_w2[layer];
    const float bout_r = (lcol < OO) ? b_out[lcol] : 0.f;

    f16x8 badj[5];                 // adj B-frags: register-resident
    #pragma unroll
    for (int kk = 0; kk < 5; ++kk)
        badj[kk] = *(const f16x8*)&wmats[((size_t)(wave * 5 + kk) * 64 + lane) * 8];

    const _Float16* gwp = wmats + (size_t)(1 + layer * 8) * MATSZ;
    __syncthreads();

    // rolling projection accumulator (layer-1 WGs, waves 0-5)
    f32x4 pacc = {0.f, 0.f, 0.f, 0.f};
    int cur_i = wave >> 1;
    const int pmt = wave & 1;

    auto proj_step = [&](int tp) {
        if (cur_i > HH - 1) return;
        const int s = cur_i * TT - tp * HH;   // t' = f - s
        if (s > HH - 1) return;
        const int lc = (lcol < OO) ? lcol : 0;
        #pragma unroll
        for (int kk = 0; kk < 5; ++kk) {
            f16x8 b;
            #pragma unroll
            for (int e = 0; e < 8; ++e) {
                int f  = kk * 32 + qoff + e;
                int tq = f - s;
                bool ok = (lcol < OO) && (tq >= 0) && (tq < TT) && (f < HH);
                int tqc = tq < 0 ? 0 : (tq > TT - 1 ? TT - 1 : tq);
                b[e] = ok ? wout_s[lc][tqc] : (_Float16)0.f;
            }
            f16x8 a = *(const f16x8*)&st_h[((pmt * 5 + kk) * 64 + lane) * 8];
            pacc = __builtin_amdgcn_mfma_f32_16x16x32_f16(a, b, pacc, 0, 0, 0);
        }
        if (s <= 28) {     // plane complete -> pure store
            if (lcol < OO) {
                #pragma unroll
                for (int r = 0; r < 4; ++r)
                    out[(size_t)(b0 + pmt * 16 + (quad << 2) + r) * (HH * OO)
                        + cur_i * OO + lcol] = pacc[r] + bout_r;
            }
            pacc = (f32x4){0.f, 0.f, 0.f, 0.f};
            cur_i += 3;
        }
    };

    float cgr[2][4];   // GCN'd c (register-resident; partition == elementwise)

    for (int t = 0; t < TT; ++t) {
        // ---- phase A (R5 order): x loads first, stage mats 0,1, then use ----
        float4 vx[5];
        if (wave >= 6) {
            const int e0 = tid - 384;
            #pragma unroll
            for (int it = 0; it < 5; ++it) {
                int e = e0 + it * 256;          // 0..1279
                int m = e / 40, q = e % 40, f = q << 2;
                float4 v = make_float4(0.f, 0.f, 0.f, 0.f);
                if (f + 4 <= HH) v = *(const float4*)&x[((size_t)(b0 + m) * TT + t) * HH + f];
                vx[it] = v;
            }
        }
        stage_mat(wbuf,         gwp,         wave, lane);
        stage_mat(wbuf + MATSZ, gwp + MATSZ, wave, lane);

        if (wave >= 6) {
            const int e0 = tid - 384;
            #pragma unroll
            for (int it = 0; it < 5; ++it) {
                int e = e0 + it * 256;
                int m = e / 40, q = e % 40, f = q << 2;
                f16x4 h4 = {(_Float16)vx[it].x, (_Float16)vx[it].y,
                            (_Float16)vx[it].z, (_Float16)vx[it].w};
                *(f16x4*)&xbf[fidx(m, f)] = h4;   // f=156 chunk zeroes the pad
            }
        } else if (layer && t > 0) {
            proj_step(t - 1);
        }
        __syncthreads();   // B1: full drain (mats 0,1 landed; throttle point)

        // ---- GCN (t>0): per state matrix S (0:c->regs, 1:h->LDS) ----
        if (t > 0) {
            #pragma unroll
            for (int S = 0; S < 2; ++S) {
                const _Float16* Ab = S ? st_h : st_c;
                #pragma unroll
                for (int mt = 0; mt < 2; ++mt) {
                    f32x4 a1 = {0.f, 0.f, 0.f, 0.f};
                    #pragma unroll
                    for (int kk = 0; kk < 5; ++kk) {
                        f16x8 a = *(const f16x8*)&Ab[((mt * 5 + kk) * 64 + lane) * 8];
                        a1 = __builtin_amdgcn_mfma_f32_16x16x32_f16(a, badj[kk], a1, 0, 0, 0);
                    }
                    #pragma unroll
                    for (int r = 0; r < 4; ++r) {
                        float v = a1[r] * gw1;
                        tmp[mt * 2560 + colb + ((quad << 2) + r) * 8] =
                            (_Float16)(v > 0.f ? v : 0.f);
                    }
                }
                __syncthreads();
                #pragma unroll
                for (int mt = 0; mt < 2; ++mt) {
                    f32x4 a2 = {0.f, 0.f, 0.f, 0.f};
                    #pragma unroll
                    for (int kk = 0; kk < 5; ++kk) {
                        f16x8 a = *(const f16x8*)&tmp[((mt * 5 + kk) * 64 + lane) * 8];
                        a2 = __builtin_amdgcn_mfma_f32_16x16x32_f16(a, badj[kk], a2, 0, 0, 0);
                    }
                    if (S == 0) {
                        #pragma unroll
                        for (int r = 0; r < 4; ++r)
                            cgr[mt][r] = (float)(_Float16)sigm(a2[r] * gw2);  // keep f16 rounding
                    } else {
                        #pragma unroll
                        for (int r = 0; r < 4; ++r)
                            st_h[mt * 2560 + colb + ((quad << 2) + r) * 8] =
                                (_Float16)sigm(a2[r] * gw2);
                    }
                }
                __syncthreads();
            }
        } else {
            #pragma unroll
            for (int mt = 0; mt < 2; ++mt)
                #pragma unroll
                for (int r = 0; r < 4; ++r) cgr[mt][r] = 0.f;
        }

        // ---- A-frags once into registers ----
        f16x8 ax[2][5], ah[2][5];
        #pragma unroll
        for (int mt = 0; mt < 2; ++mt)
            #pragma unroll
            for (int kk = 0; kk < 5; ++kk) {
                ax[mt][kk] = *(const f16x8*)&xbf[((mt * 5 + kk) * 64 + lane) * 8];
                ah[mt][kk] = *(const f16x8*)&st_h[((mt * 5 + kk) * 64 + lane) * 8];
            }

        // ---- gates: R5-proven ledger. enter vmcnt=0 (B1 drained).
        //  i0: cnt(5) nop, read mat0, stage mat2. i1: nop, read1, stage3.
        //  i2..i6: cnt(5) drains mat m, read m, stage m+2 (m<6).
        //  i7: cnt(0) drains mat7, read7. Uniform for all t.
        f32x4 acc[8];
        #pragma unroll
        for (int a2i = 0; a2i < 8; ++a2i) acc[a2i] = (f32x4){0.f, 0.f, 0.f, 0.f};
        #pragma unroll
        for (int m = 0; m < 8; ++m) {
            if (m < 7) asm volatile("s_waitcnt vmcnt(5)" ::: "memory");
            else       asm volatile("s_waitcnt vmcnt(0)" ::: "memory");
            __builtin_amdgcn_sched_barrier(0);
            const _Float16* wbc = wbuf + (size_t)(m & 1) * MATSZ;
            f16x8 bw[5];
            #pragma unroll
            for (int kk = 0; kk < 5; ++kk)
                bw[kk] = *(const f16x8*)&wbc[((size_t)(wave * 5 + kk) * 64 + lane) * 8];
            const int g = m >> 1;
            #pragma unroll
            for (int mt = 0; mt < 2; ++mt) {
                #pragma unroll
                for (int kk = 0; kk < 5; ++kk) {
                    f16x8 a = (m & 1) ? ah[mt][kk] : ax[mt][kk];
                    acc[g * 2 + mt] = __builtin_amdgcn_mfma_f32_16x16x32_f16(
                        a, bw[kk], acc[g * 2 + mt], 0, 0, 0);
                }
            }
            if (m < 6) {
                asm volatile("s_waitcnt lgkmcnt(0)" ::: "memory");  // bw reads done
                __builtin_amdgcn_sched_barrier(0);
                stage_mat(wbuf + (size_t)(m & 1) * MATSZ, gwp + (size_t)(m + 2) * MATSZ,
                          wave, lane);
            }
        }
        __syncthreads();   // B4: ah/ax reads (all waves) done before state writes

        // ---- elementwise LSTM update (c from registers) ----
        #pragma unroll
        for (int mt = 0; mt < 2; ++mt) {
            #pragma unroll
            for (int r = 0; r < 4; ++r) {
                float i_ = sigm(acc[0 * 2 + mt][r] + bias_r[0]);
                float f_ = sigm(acc[1 * 2 + mt][r] + bias_r[1]);
                float o_ = sigm(acc[2 * 2 + mt][r] + bias_r[2]);
                float g_ = tanh_(acc[3 * 2 + mt][r] + bias_r[3]);
                float c_new = f_ * cgr[mt][r] + i_ * g_;
                float h_new = o_ * tanh_(c_new);
                const int fi = mt * 2560 + colb + ((quad << 2) + r) * 8;
                st_c[fi] = (_Float16)c_new;
                st_h[fi] = (_Float16)h_new;
            }
        }
        __syncthreads();   // B5: updates visible to next phase A / GCN
    }

    // final projection flush + epilogue
    if (layer && wave < 6) proj_step(TT - 1);

    float* hn = out + (size_t)4096 * HH * OO;
    float* cn = hn + (size_t)2 * 4096 * HH;
    for (int e = tid; e < BB * HH; e += 640) {
        int m = e / HH;
        int f = e % HH;
        size_t off = ((size_t)layer * 4096 + b0 + m) * HH + f;
        int fi = fidx(m, f);
        hn[off] = (float)st_h[fi];
        cn[off] = (float)st_c[fi];
    }
}

// ---------------------------------------------------------------------------
extern "C" void kernel_launch(void* const* d_in, const int* in_sizes, int n_in,
                              void* d_out, int out_size, void* d_ws, size_t ws_size,
                              hipStream_t stream) {
    const float* x    = (const float*)d_in[0];
    const float* adj  = (const float*)d_in[1];
    const float* Wix  = (const float*)d_in[2];  const float* bix = (const float*)d_in[3];
    const float* Wih  = (const float*)d_in[4];  const float* bih = (const float*)d_in[5];
    const float* Wfx  = (const float*)d_in[6];  const float* bfx = (const float*)d_in[7];
    const float* Wfh  = (const float*)d_in[8];  const float* bfh = (const float*)d_in[9];
    const float* Wcx  = (const float*)d_in[10]; const float* bcx = (const float*)d_in[11];
    const float* Wch  = (const float*)d_in[12]; const float* bch = (const float*)d_in[13];
    const float* Wox  = (const float*)d_in[14]; const float* box_ = (const float*)d_in[15];
    const float* Woh  = (const float*)d_in[16]; const float* boh = (const float*)d_in[17];
    const float* gw1  = (const float*)d_in[18];
    const float* gw2  = (const float*)d_in[19];
    const float* Wout = (const float*)d_in[20];
    const float* bout = (const float*)d_in[21];

    _Float16* wmats   = (_Float16*)d_ws;
    float* bias_comb  = (float*)((char*)d_ws + (size_t)17 * MATSZ * sizeof(_Float16));
    float* out        = (float*)d_out;

    prep_kernel<<<(17 * MATSZ + 2 * 4 * HP + 255) / 256, 256, 0, stream>>>(
        adj, Wix, Wih, Wfx, Wfh, Wcx, Wch, Wox, Woh,
        bix, bih, bfx, bfh, bcx, bch, box_, boh, wmats, bias_comb);

    (void)hipFuncSetAttribute((const void*)lstm_main,
                              hipFuncAttributeMaxDynamicSharedMemorySize,
                              2 * MATSZ * sizeof(_Float16));

    lstm_main<<<256, 640, 2 * MATSZ * sizeof(_Float16), stream>>>(
        x, wmats, bias_comb, Wout, bout, gw1, gw2, out);
}

// Round 10
// 3304.203 us; speedup vs baseline: 1.0896x; 1.0896x over previous
//
#include <hip/hip_runtime.h>

// MyLSTM_GCN: B=4096, T=128, H=156, L=2, O=12
// R12: identical resubmit of R11 (GPUAcquisitionTimeout - never ran).
// R11: cut weight L2 demand 37% via persistent register weights.
//  R10 falsified the barrier-throttle theory (full syncthreads, FETCH still
//  4.6e6 KB = 9x R5). Request stream is byte-identical to R5 -> L2 thrash is
//  timing-triggered & bistable; not bisectable in one shot. Robust lever:
//  reduce demanded bytes. 3 gate mats (Wix,Wih,Wfh) live in 60 VGPRs for the
//  whole kernel (loaded once); only 5 mats stream through the LDS dbuf.
//  Paid for by dropping ax/ah reg A-frags (frag-major LDS reads are
//  conflict-free, re-read is cheap). Per-acc MFMA order preserved ->
//  bit-identical numerics. Uniform vmcnt ledger, no tail case:
//   phase A stages {2,4}; B1 drains. s0: read2(f,x) stage5. s1: read4(o,x)
//   stage6. persistent 0(i,x) 1(i,h) 3(f,h) [covers 5,6 latency].
//   s2: vm(5) read5(o,h) stage7. s3: vm(5) read6(c,x). s4: vm(0) read7(c,h).

#define HH 156
#define HP 160
#define TT 128
#define OO 12
#define BB 32             // batches per WG
#define MATSZ 25600       // 160x160 f16 per gate/adj matrix, frag-major
#define FMAT  5120        // 32x160 f16 per frag-major state matrix

typedef _Float16 f16x8 __attribute__((ext_vector_type(8)));
typedef _Float16 f16x4 __attribute__((ext_vector_type(4)));
typedef float    f32x4 __attribute__((ext_vector_type(4)));

__device__ __forceinline__ float sigm(float v) { return 1.0f / (1.0f + __expf(-v)); }
__device__ __forceinline__ float tanh_(float v) { return 2.0f / (1.0f + __expf(-2.0f * v)) - 1.0f; }

// ---------------------------------------------------------------------------
// Phase 0 (unchanged, verified): 17 matrices frag-major f16 + combined biases.
// mat id: 0 = adj; 1 + j*8 + (g*2+s), g: i,f,o,c; s=0:Wx,1:Wh.
// ---------------------------------------------------------------------------
__global__ __launch_bounds__(256) void prep_kernel(
    const float* __restrict__ adj,
    const float* __restrict__ Wix, const float* __restrict__ Wih,
    const float* __restrict__ Wfx, const float* __restrict__ Wfh,
    const float* __restrict__ Wcx, const float* __restrict__ Wch,
    const float* __restrict__ Wox, const float* __restrict__ Woh,
    const float* __restrict__ bix, const float* __restrict__ bih,
    const float* __restrict__ bfx, const float* __restrict__ bfh,
    const float* __restrict__ bcx, const float* __restrict__ bch,
    const float* __restrict__ box_, const float* __restrict__ boh,
    _Float16* __restrict__ wmats, float* __restrict__ bias_comb)
{
    int idx = blockIdx.x * 256 + threadIdx.x;
    if (idx < 17 * MATSZ) {
        int mat = idx / MATSZ;
        int r   = idx % MATSZ;
        int e    = r & 7;
        int lane = (r >> 3) & 63;
        int c    = r >> 9;            // 0..49
        int lcol = lane & 15, quad = lane >> 4;
        int kk = c % 5, w = c / 5;
        int nrow = w * 16 + lcol;
        int k    = kk * 32 + quad * 8 + e;
        float v = 0.f;
        if (nrow < HH && k < HH) {
            if (mat == 0) {
                v = adj[nrow * HH + k];
            } else {
                int m2 = mat - 1;
                int s  = m2 & 1;
                int jg = m2 >> 1;
                int j  = jg >> 2;
                int g  = jg & 3;
                const float* W;
                if (s == 0) W = (g == 0) ? Wix : (g == 1) ? Wfx : (g == 2) ? Wox : Wcx;
                else        W = (g == 0) ? Wih : (g == 1) ? Wfh : (g == 2) ? Woh : Wch;
                v = W[j * (HH * HH) + nrow * HH + k];
            }
        }
        wmats[idx] = (_Float16)v;
    } else if (idx < 17 * MATSZ + 2 * 4 * HP) {
        int r = idx - 17 * MATSZ;
        int j = r / (4 * HP);
        int g = (r % (4 * HP)) / HP;
        int nn = r % HP;
        float v = 0.f;
        if (nn < HH) {
            const float* Bx = (g == 0) ? bix : (g == 1) ? bfx : (g == 2) ? box_ : bcx;
            const float* Bh = (g == 0) ? bih : (g == 1) ? bfh : (g == 2) ? boh : bch;
            v = Bx[j * HH + nn] + Bh[j * HH + nn];
        }
        bias_comb[r] = v;
    }
}

// async 16B/lane DMA: lane L reads g+L*16B, writes wave-uniform ldsbase + L*16B
__device__ __forceinline__ void dma16(const _Float16* g, _Float16* l) {
    __builtin_amdgcn_global_load_lds(
        (const __attribute__((address_space(1))) void*)(g),
        (__attribute__((address_space(3))) void*)(l), 16, 0, 0);
}

// stage one frag-major matrix: wave w copies its own chunks w*5..w*5+4 (1KB each)
__device__ __forceinline__ void stage_mat(_Float16* buf, const _Float16* gmat,
                                          int wave, int lane) {
    #pragma unroll
    for (int i = 0; i < 5; ++i) {
        const int c = wave * 5 + i;
        dma16(gmat + (size_t)c * 512 + lane * 8, buf + (size_t)c * 512);
    }
}

// f16 index of element (row m, col k) in a 32x160 frag-major matrix
__device__ __forceinline__ int fidx(int m, int k) {
    return (((m >> 4) * 5 + (k >> 5)) * 64 + ((k >> 3) & 3) * 16 + (m & 15)) * 8 + (k & 7);
}

// ---------------------------------------------------------------------------
// Main recurrent kernel: 256 WGs x 640 threads (10 waves, 1 WG/CU).
// bid&1 = layer, bid>>1 = batch group (M=32). Wave w owns cols n = w*16+lcol.
// ---------------------------------------------------------------------------
__global__ __launch_bounds__(640, 3) void lstm_main(
    const float* __restrict__ x,
    const _Float16* __restrict__ wmats,
    const float* __restrict__ bias_comb,
    const float* __restrict__ w_out,
    const float* __restrict__ b_out,
    const float* __restrict__ gcn_w1,
    const float* __restrict__ gcn_w2,
    float* __restrict__ out)
{
    __shared__ __align__(16) _Float16 st_c[FMAT];       // frag-major 32x160
    __shared__ __align__(16) _Float16 st_h[FMAT];
    __shared__ __align__(16) _Float16 tmp[FMAT];        // GCN mid, per-S
    __shared__ __align__(16) _Float16 xbf[FMAT];
    __shared__ __align__(16) _Float16 wout_s[OO][TT + 8];
    extern __shared__ __align__(16) _Float16 wbuf[];    // 2 x 25600 f16 (100 KB)

    const int tid   = threadIdx.x;
    const int wave  = tid >> 6;
    const int lane  = tid & 63;
    const int lcol  = lane & 15;
    const int quad  = lane >> 4;
    const int qoff  = quad << 3;
    const int layer = blockIdx.x & 1;
    const int b0    = (blockIdx.x >> 1) << 5;
    const int n     = (wave << 4) + lcol;
    // frag col-base for scalar writes at col n: fidx(m,n) = (m>>4)*2560 + colb + (m&15)*8
    const int colb  = ((n >> 5) * 64 + ((n >> 3) & 3) * 16) * 8 + (n & 7);

    for (int e = tid; e < FMAT; e += 640) {
        st_c[e] = (_Float16)0.f;
        st_h[e] = (_Float16)0.f;
    }
    for (int e = tid; e < OO * TT; e += 640) wout_s[e / TT][e % TT] = (_Float16)w_out[e];

    float bias_r[4];
    #pragma unroll
    for (int g = 0; g < 4; ++g)
        bias_r[g] = bias_comb[(layer * 4 + g) * HP + n];
    const float gw1 = gcn_w1[layer];
    const float gw2 = gcn_w2[layer];
    const float bout_r = (lcol < OO) ? b_out[lcol] : 0.f;

    f16x8 badj[5];                 // adj B-frags: register-resident
    #pragma unroll
    for (int kk = 0; kk < 5; ++kk)
        badj[kk] = *(const f16x8*)&wmats[((size_t)(wave * 5 + kk) * 64 + lane) * 8];

    const _Float16* gwp = wmats + (size_t)(1 + layer * 8) * MATSZ;

    // persistent gate weights: mat0=Wix, mat1=Wih, mat3=Wfh (60 VGPRs, whole kernel)
    f16x8 wreg[3][5];
    #pragma unroll
    for (int kk = 0; kk < 5; ++kk) {
        wreg[0][kk] = *(const f16x8*)&gwp[(size_t)0 * MATSZ + ((size_t)(wave * 5 + kk) * 64 + lane) * 8];
        wreg[1][kk] = *(const f16x8*)&gwp[(size_t)1 * MATSZ + ((size_t)(wave * 5 + kk) * 64 + lane) * 8];
        wreg[2][kk] = *(const f16x8*)&gwp[(size_t)3 * MATSZ + ((size_t)(wave * 5 + kk) * 64 + lane) * 8];
    }
    __syncthreads();

    // rolling projection accumulator (layer-1 WGs, waves 0-5)
    f32x4 pacc = {0.f, 0.f, 0.f, 0.f};
    int cur_i = wave >> 1;
    const int pmt = wave & 1;

    auto proj_step = [&](int tp) {
        if (cur_i > HH - 1) return;
        const int s = cur_i * TT - tp * HH;   // t' = f - s
        if (s > HH - 1) return;
        const int lc = (lcol < OO) ? lcol : 0;
        #pragma unroll
        for (int kk = 0; kk < 5; ++kk) {
            f16x8 b;
            #pragma unroll
            for (int e = 0; e < 8; ++e) {
                int f  = kk * 32 + qoff + e;
                int tq = f - s;
                bool ok = (lcol < OO) && (tq >= 0) && (tq < TT) && (f < HH);
                int tqc = tq < 0 ? 0 : (tq > TT - 1 ? TT - 1 : tq);
                b[e] = ok ? wout_s[lc][tqc] : (_Float16)0.f;
            }
            f16x8 a = *(const f16x8*)&st_h[((pmt * 5 + kk) * 64 + lane) * 8];
            pacc = __builtin_amdgcn_mfma_f32_16x16x32_f16(a, b, pacc, 0, 0, 0);
        }
        if (s <= 28) {     // plane complete -> pure store
            if (lcol < OO) {
                #pragma unroll
                for (int r = 0; r < 4; ++r)
                    out[(size_t)(b0 + pmt * 16 + (quad << 2) + r) * (HH * OO)
                        + cur_i * OO + lcol] = pacc[r] + bout_r;
            }
            pacc = (f32x4){0.f, 0.f, 0.f, 0.f};
            cur_i += 3;
        }
    };

    float cgr[2][4];   // GCN'd c (register-resident; partition == elementwise)
    f32x4 acc[8];      // gate accumulators [g*2+mt], g: 0=i,1=f,2=o,3=c

    // one gate matrix: A from LDS (frag-major), B frags given
    auto gate_mat = [&](const f16x8* bw, const _Float16* Ab, int g) {
        #pragma unroll
        for (int mt = 0; mt < 2; ++mt)
            #pragma unroll
            for (int kk = 0; kk < 5; ++kk) {
                f16x8 a = *(const f16x8*)&Ab[((mt * 5 + kk) * 64 + lane) * 8];
                acc[g * 2 + mt] = __builtin_amdgcn_mfma_f32_16x16x32_f16(
                    a, bw[kk], acc[g * 2 + mt], 0, 0, 0);
            }
    };
    auto read_bw = [&](const _Float16* wbc, f16x8* bw) {
        #pragma unroll
        for (int kk = 0; kk < 5; ++kk)
            bw[kk] = *(const f16x8*)&wbc[((size_t)(wave * 5 + kk) * 64 + lane) * 8];
    };

    for (int t = 0; t < TT; ++t) {
        // ---- phase A: x loads first, stage mats 2,4, proj / x-stage ----
        float4 vx[5];
        if (wave >= 6) {
            const int e0 = tid - 384;
            #pragma unroll
            for (int it = 0; it < 5; ++it) {
                int e = e0 + it * 256;          // 0..1279
                int m = e / 40, q = e % 40, f = q << 2;
                float4 v = make_float4(0.f, 0.f, 0.f, 0.f);
                if (f + 4 <= HH) v = *(const float4*)&x[((size_t)(b0 + m) * TT + t) * HH + f];
                vx[it] = v;
            }
        }
        stage_mat(wbuf,         gwp + (size_t)2 * MATSZ, wave, lane);   // Wfx
        stage_mat(wbuf + MATSZ, gwp + (size_t)4 * MATSZ, wave, lane);   // Wox

        if (wave >= 6) {
            const int e0 = tid - 384;
            #pragma unroll
            for (int it = 0; it < 5; ++it) {
                int e = e0 + it * 256;
                int m = e / 40, q = e % 40, f = q << 2;
                f16x4 h4 = {(_Float16)vx[it].x, (_Float16)vx[it].y,
                            (_Float16)vx[it].z, (_Float16)vx[it].w};
                *(f16x4*)&xbf[fidx(m, f)] = h4;   // f=156 chunk zeroes the pad
            }
        } else if (layer && t > 0) {
            proj_step(t - 1);
        }
        __syncthreads();   // B1: full drain (mats 2,4 landed)

        // ---- GCN (t>0): per state matrix S (0:c->regs, 1:h->LDS) ----
        if (t > 0) {
            #pragma unroll
            for (int S = 0; S < 2; ++S) {
                const _Float16* Ab = S ? st_h : st_c;
                #pragma unroll
                for (int mt = 0; mt < 2; ++mt) {
                    f32x4 a1 = {0.f, 0.f, 0.f, 0.f};
                    #pragma unroll
                    for (int kk = 0; kk < 5; ++kk) {
                        f16x8 a = *(const f16x8*)&Ab[((mt * 5 + kk) * 64 + lane) * 8];
                        a1 = __builtin_amdgcn_mfma_f32_16x16x32_f16(a, badj[kk], a1, 0, 0, 0);
                    }
                    #pragma unroll
                    for (int r = 0; r < 4; ++r) {
                        float v = a1[r] * gw1;
                        tmp[mt * 2560 + colb + ((quad << 2) + r) * 8] =
                            (_Float16)(v > 0.f ? v : 0.f);
                    }
                }
                __syncthreads();
                #pragma unroll
                for (int mt = 0; mt < 2; ++mt) {
                    f32x4 a2 = {0.f, 0.f, 0.f, 0.f};
                    #pragma unroll
                    for (int kk = 0; kk < 5; ++kk) {
                        f16x8 a = *(const f16x8*)&tmp[((mt * 5 + kk) * 64 + lane) * 8];
                        a2 = __builtin_amdgcn_mfma_f32_16x16x32_f16(a, badj[kk], a2, 0, 0, 0);
                    }
                    if (S == 0) {
                        #pragma unroll
                        for (int r = 0; r < 4; ++r)
                            cgr[mt][r] = (float)(_Float16)sigm(a2[r] * gw2);  // keep f16 rounding
                    } else {
                        #pragma unroll
                        for (int r = 0; r < 4; ++r)
                            st_h[mt * 2560 + colb + ((quad << 2) + r) * 8] =
                                (_Float16)sigm(a2[r] * gw2);
                    }
                }
                __syncthreads();
            }
        } else {
            #pragma unroll
            for (int mt = 0; mt < 2; ++mt)
                #pragma unroll
                for (int r = 0; r < 4; ++r) cgr[mt][r] = 0.f;
        }

        // ---- gates: 3 persistent (regs) + 5 streamed (LDS dbuf) ----
        // ledger: enter vmcnt=0. s0: read2 stage5 (+5). s1: read4 stage6 (+5=10).
        // persistent block (covers 5,6). s2: vm(5)->5 done, read5, stage7 (=10).
        // s3: vm(5)->6 done, read6. s4: vm(0)->7 done, read7. Uniform all t.
        #pragma unroll
        for (int a2i = 0; a2i < 8; ++a2i) acc[a2i] = (f32x4){0.f, 0.f, 0.f, 0.f};
        f16x8 bw[5];

        read_bw(wbuf, bw);          gate_mat(bw, xbf, 1);      // mat2 = Wfx
        asm volatile("s_waitcnt lgkmcnt(0)" ::: "memory");
        __builtin_amdgcn_sched_barrier(0);
        stage_mat(wbuf, gwp + (size_t)5 * MATSZ, wave, lane);  // Woh -> buf0

        read_bw(wbuf + MATSZ, bw);  gate_mat(bw, xbf, 2);      // mat4 = Wox
        asm volatile("s_waitcnt lgkmcnt(0)" ::: "memory");
        __builtin_amdgcn_sched_barrier(0);
        stage_mat(wbuf + MATSZ, gwp + (size_t)6 * MATSZ, wave, lane);  // Wcx -> buf1

        gate_mat(wreg[0], xbf, 0);                             // Wix
        gate_mat(wreg[1], st_h, 0);                            // Wih
        gate_mat(wreg[2], st_h, 1);                            // Wfh

        asm volatile("s_waitcnt vmcnt(5)" ::: "memory");       // mat5 landed
        __builtin_amdgcn_sched_barrier(0);
        read_bw(wbuf, bw);          gate_mat(bw, st_h, 2);     // mat5 = Woh
        asm volatile("s_waitcnt lgkmcnt(0)" ::: "memory");
        __builtin_amdgcn_sched_barrier(0);
        stage_mat(wbuf, gwp + (size_t)7 * MATSZ, wave, lane);  // Wch -> buf0

        asm volatile("s_waitcnt vmcnt(5)" ::: "memory");       // mat6 landed
        __builtin_amdgcn_sched_barrier(0);
        read_bw(wbuf + MATSZ, bw);  gate_mat(bw, xbf, 3);      // mat6 = Wcx

        asm volatile("s_waitcnt vmcnt(0)" ::: "memory");       // mat7 landed
        __builtin_amdgcn_sched_barrier(0);
        read_bw(wbuf, bw);          gate_mat(bw, st_h, 3);     // mat7 = Wch

        __syncthreads();   // B4: all LDS A/B reads done before state writes

        // ---- elementwise LSTM update (c from registers) ----
        #pragma unroll
        for (int mt = 0; mt < 2; ++mt) {
            #pragma unroll
            for (int r = 0; r < 4; ++r) {
                float i_ = sigm(acc[0 * 2 + mt][r] + bias_r[0]);
                float f_ = sigm(acc[1 * 2 + mt][r] + bias_r[1]);
                float o_ = sigm(acc[2 * 2 + mt][r] + bias_r[2]);
                float g_ = tanh_(acc[3 * 2 + mt][r] + bias_r[3]);
                float c_new = f_ * cgr[mt][r] + i_ * g_;
                float h_new = o_ * tanh_(c_new);
                const int fi = mt * 2560 + colb + ((quad << 2) + r) * 8;
                st_c[fi] = (_Float16)c_new;
                st_h[fi] = (_Float16)h_new;
            }
        }
        __syncthreads();   // B5: updates visible to next phase A / GCN
    }

    // final projection flush + epilogue
    if (layer && wave < 6) proj_step(TT - 1);

    float* hn = out + (size_t)4096 * HH * OO;
    float* cn = hn + (size_t)2 * 4096 * HH;
    for (int e = tid; e < BB * HH; e += 640) {
        int m = e / HH;
        int f = e % HH;
        size_t off = ((size_t)layer * 4096 + b0 + m) * HH + f;
        int fi = fidx(m, f);
        hn[off] = (float)st_h[fi];
        cn[off] = (float)st_c[fi];
    }
}

// ---------------------------------------------------------------------------
extern "C" void kernel_launch(void* const* d_in, const int* in_sizes, int n_in,
                              void* d_out, int out_size, void* d_ws, size_t ws_size,
                              hipStream_t stream) {
    const float* x    = (const float*)d_in[0];
    const float* adj  = (const float*)d_in[1];
    const float* Wix  = (const float*)d_in[2];  const float* bix = (const float*)d_in[3];
    const float* Wih  = (const float*)d_in[4];  const float* bih = (const float*)d_in[5];
    const float* Wfx  = (const float*)d_in[6];  const float* bfx = (const float*)d_in[7];
    const float* Wfh  = (const float*)d_in[8];  const float* bfh = (const float*)d_in[9];
    const float* Wcx  = (const float*)d_in[10]; const float* bcx = (const float*)d_in[11];
    const float* Wch  = (const float*)d_in[12]; const float* bch = (const float*)d_in[13];
    const float* Wox  = (const float*)d_in[14]; const float* box_ = (const float*)d_in[15];
    const float* Woh  = (const float*)d_in[16]; const float* boh = (const float*)d_in[17];
    const float* gw1  = (const float*)d_in[18];
    const float* gw2  = (const float*)d_in[19];
    const float* Wout = (const float*)d_in[20];
    const float* bout = (const float*)d_in[21];

    _Float16* wmats   = (_Float16*)d_ws;
    float* bias_comb  = (float*)((char*)d_ws + (size_t)17 * MATSZ * sizeof(_Float16));
    float* out        = (float*)d_out;

    prep_kernel<<<(17 * MATSZ + 2 * 4 * HP + 255) / 256, 256, 0, stream>>>(
        adj, Wix, Wih, Wfx, Wfh, Wcx, Wch, Wox, Woh,
        bix, bih, bfx, bfh, bcx, bch, box_, boh, wmats, bias_comb);

    (void)hipFuncSetAttribute((const void*)lstm_main,
                              hipFuncAttributeMaxDynamicSharedMemorySize,
                              2 * MATSZ * sizeof(_Float16));

    lstm_main<<<256, 640, 2 * MATSZ * sizeof(_Float16), stream>>>(
        x, wmats, bias_comb, Wout, bout, gw1, gw2, out);
}